// Round 3
// baseline (1892.153 us; speedup 1.0000x reference)
//
#include <hip/hip_runtime.h>
#include <hip/hip_bf16.h>

// MLA attention. Inputs are float32 per the reference (detected at runtime to
// be safe); internal compute in bf16 MFMA (no fp32 MFMA on CDNA4); output
// stored fp32 (or bf16 if inputs turn out bf16). Pipeline:
//   0. detect input dtype (bf16 inf/NaN bit-pattern scan) -> flag in ws
//   1. convert x -> bf16 [M,K]; convert+transpose weights -> bf16 [N][K]
//   2. lat = x @ W_kv                  ([M,32])
//   3. K   = lat @ W_k   -> [M,1024]   (head h = cols h*64..h*64+63)
//   4. V   = lat @ W_v   -> [B,H,dh,T] (transposed: PV B-frags contiguous)
//   5. Q   = x @ W_q     -> [M,1024]
//   6. flash attention (mfma 16x16x32, online softmax); overwrites own Q tile
//   7. out = AO @ W_o    -> d_out (fp32 if flag, else bf16)

#define T_SEQ  4096
#define NHEAD  16
#define DHEAD  64
#define DMODEL 1024
#define LATENT 32
#define BATCH  2
#define M_ROWS (BATCH * T_SEQ)

typedef __attribute__((ext_vector_type(8))) short bf16x8;
typedef __attribute__((ext_vector_type(4))) float f32x4;

__device__ __forceinline__ short f2bf(float f) {
  __hip_bfloat16 h = __float2bfloat16(f);
  return __builtin_bit_cast(short, h);
}

// ------------------------------------------------------------- dtype detect
// One block scans the first 1M shorts of x for bf16 inf/NaN bit patterns
// (exponent field all-ones). fp32 N(0,1) data: low halves are ~random 16-bit
// -> ~2000 hits. True bf16 N(0,1) data: zero hits. flag=1 -> fp32 inputs.
__global__ __launch_bounds__(256)
void detect_dtype(const unsigned short* __restrict__ xs, int nshorts,
                  int* __restrict__ flag) {
  __shared__ int cnt[256];
  int c = 0;
  for (int i = threadIdx.x; i < nshorts; i += 256) {
    if ((xs[i] & 0x7F80u) == 0x7F80u) ++c;
  }
  cnt[threadIdx.x] = c;
  __syncthreads();
  for (int s = 128; s > 0; s >>= 1) {
    if (threadIdx.x < s) cnt[threadIdx.x] += cnt[threadIdx.x + s];
    __syncthreads();
  }
  if (threadIdx.x == 0) flag[0] = (cnt[0] > 0) ? 1 : 0;
}

// ------------------------------------------------------------- ingress conv
__global__ __launch_bounds__(256)
void convert_in(const void* __restrict__ src, short* __restrict__ dst, int n,
                const int* __restrict__ flag) {
  int i = blockIdx.x * 256 + threadIdx.x;
  if (i >= n) return;
  if (flag[0]) dst[i] = f2bf(((const float*)src)[i]);
  else         dst[i] = ((const short*)src)[i];
}

// convert + transpose: src [K,N] -> dst [N,K] bf16
__global__ __launch_bounds__(256)
void convert_transpose(const void* __restrict__ src, short* __restrict__ dst,
                       int K, int N, const int* __restrict__ flag) {
  int idx = blockIdx.x * 256 + threadIdx.x;
  if (idx >= K * N) return;
  int k = idx / N;
  int n = idx - k * N;
  short v;
  if (flag[0]) v = f2bf(((const float*)src)[idx]);
  else         v = ((const short*)src)[idx];
  dst[n * K + k] = v;
}

// ---------------------------------------------------------------- GEMM
// C[M,N] = A[M,K] @ B[K,N], Bt = B^T ([N][K] row-major, bf16).
// One wave computes a 16(M) x 64(N) tile; 4 waves/block.
// out_mode 0: bf16 row-major [M,N]
// out_mode 2: bf16 [B,H,dh,T] (V^T; requires N==DMODEL)
// out_mode 3: row-major to Cf (fp32) if flag[0], else to Cs (bf16)
__global__ __launch_bounds__(256)
void gemm_bt_kernel(const short* __restrict__ A, const short* __restrict__ Bt,
                    short* __restrict__ Cs, float* __restrict__ Cf,
                    const int* __restrict__ flag,
                    int M, int K, int N, int out_mode) {
  const int tid  = threadIdx.x;
  const int wv   = tid >> 6;
  const int lane = tid & 63;
  const int quad = lane >> 4;
  const int l16  = lane & 15;

  const int Nw = (N + 63) >> 6;
  const int gw = blockIdx.x * 4 + wv;
  const int mt = gw / Nw;
  const int nt = gw - mt * Nw;
  const int m0 = mt * 16;
  const int n0 = nt * 64;
  if (m0 >= M) return;

  const int fl = (out_mode == 3) ? flag[0] : 0;

  f32x4 acc[4] = {};
  const short* Ap = A + (size_t)(m0 + l16) * K + quad * 8;

  for (int k0 = 0; k0 < K; k0 += 32) {
    bf16x8 a = *(const bf16x8*)(Ap + k0);
#pragma unroll
    for (int f = 0; f < 4; ++f) {
      const int n = n0 + f * 16 + l16;
      if (n < N) {   // wave-uniform per f (N multiple of 16)
        bf16x8 b = *(const bf16x8*)(Bt + (size_t)n * K + k0 + quad * 8);
        acc[f] = __builtin_amdgcn_mfma_f32_16x16x32_bf16(a, b, acc[f], 0, 0, 0);
      }
    }
  }

#pragma unroll
  for (int f = 0; f < 4; ++f) {
    const int n = n0 + f * 16 + l16;
    if (n >= N) continue;
#pragma unroll
    for (int r = 0; r < 4; ++r) {
      const int m = m0 + quad * 4 + r;     // C/D layout: row=quad*4+r, col=l16
      if (out_mode == 2) {                 // V^T scatter
        const int b  = m >> 12;            // T_SEQ = 4096
        const int t  = m & (T_SEQ - 1);
        const int h  = n >> 6;             // DHEAD = 64
        const int dh = n & 63;
        Cs[((size_t)(b * NHEAD + h) * DHEAD + dh) * T_SEQ + t] = f2bf(acc[f][r]);
      } else {
        const size_t idx = (size_t)m * N + n;
        if (fl) Cf[idx] = acc[f][r];
        else    Cs[idx] = f2bf(acc[f][r]);
      }
    }
  }
}

// ---------------------------------------------------------------- attention
// One wave per 16-query tile of one (b,h). 32-key steps.
// Q,K natural bf16 [M,1024] (head = col block h*64); V in [B,H,dh,T].
// Output overwrites this block's own Q region (block-private: Q fully read
// into registers before the loop; no other block touches these rows+cols).
__global__ __launch_bounds__(256)
void attn_kernel(short* __restrict__ Qb, const short* __restrict__ Kb,
                 const short* __restrict__ Vt) {
  __shared__ short Plds[4][2][16 * 40];  // per-wave double-buffered 16x32 P

  const int tid  = threadIdx.x;
  const int wv   = tid >> 6;
  const int lane = tid & 63;
  const int quad = lane >> 4;
  const int l16  = lane & 15;

  const int bh = blockIdx.x >> 6;        // 64 q-chunks per (b,h)
  const int qc = blockIdx.x & 63;
  const int q0 = qc * 64 + wv * 16;
  const int b  = bh >> 4;
  const int h  = bh & 15;

  short*       Qp  = Qb + (size_t)b * T_SEQ * DMODEL + h * DHEAD;
  const short* Kp  = Kb + (size_t)b * T_SEQ * DMODEL + h * DHEAD;
  const short* Vbh = Vt + ((size_t)bh) * DHEAD * T_SEQ;   // [dh][T]

  const bf16x8 qa0 = *(const bf16x8*)(Qp + (size_t)(q0 + l16) * DMODEL + quad * 8);
  const bf16x8 qa1 = *(const bf16x8*)(Qp + (size_t)(q0 + l16) * DMODEL + 32 + quad * 8);

  f32x4 o[4] = {};
  float mrow[4], lrow[4];
#pragma unroll
  for (int r = 0; r < 4; ++r) { mrow[r] = -1e30f; lrow[r] = 0.0f; }

  int pb = 0;

  for (int k0 = 0; k0 < q0 + 16; k0 += 32) {
    // ---- S = Q K^T for 16q x 32k
    f32x4 s0 = {}, s1 = {};
    {
      bf16x8 b00 = *(const bf16x8*)(Kp + (size_t)(k0 + l16) * DMODEL + quad * 8);
      bf16x8 b01 = *(const bf16x8*)(Kp + (size_t)(k0 + l16) * DMODEL + 32 + quad * 8);
      s0 = __builtin_amdgcn_mfma_f32_16x16x32_bf16(qa0, b00, s0, 0, 0, 0);
      s0 = __builtin_amdgcn_mfma_f32_16x16x32_bf16(qa1, b01, s0, 0, 0, 0);
      bf16x8 b10 = *(const bf16x8*)(Kp + (size_t)(k0 + 16 + l16) * DMODEL + quad * 8);
      bf16x8 b11 = *(const bf16x8*)(Kp + (size_t)(k0 + 16 + l16) * DMODEL + 32 + quad * 8);
      s1 = __builtin_amdgcn_mfma_f32_16x16x32_bf16(qa0, b10, s1, 0, 0, 0);
      s1 = __builtin_amdgcn_mfma_f32_16x16x32_bf16(qa1, b11, s1, 0, 0, 0);
    }

    // ---- online softmax (C-layout: row=quad*4+r, col=l16; reduce over the
    // 16 lanes of the quad group via xor shuffles 1/2/4/8)
    const int kc0 = k0 + l16;
    const int kc1 = k0 + 16 + l16;
    float p0[4], p1[4];
#pragma unroll
    for (int r = 0; r < 4; ++r) {
      const int q = q0 + quad * 4 + r;
      float v0 = s0[r] * 0.125f;           // 1/sqrt(64)
      float v1 = s1[r] * 0.125f;
      if (kc0 > q) v0 = -1e9f;
      if (kc1 > q) v1 = -1e9f;
      float mx = fmaxf(v0, v1);
      mx = fmaxf(mx, __shfl_xor(mx, 1));
      mx = fmaxf(mx, __shfl_xor(mx, 2));
      mx = fmaxf(mx, __shfl_xor(mx, 4));
      mx = fmaxf(mx, __shfl_xor(mx, 8));
      const float mnew  = fmaxf(mrow[r], mx);
      const float alpha = __expf(mrow[r] - mnew);
      mrow[r] = mnew;
      const float e0 = __expf(v0 - mnew);
      const float e1 = __expf(v1 - mnew);
      float sum = e0 + e1;
      sum += __shfl_xor(sum, 1);
      sum += __shfl_xor(sum, 2);
      sum += __shfl_xor(sum, 4);
      sum += __shfl_xor(sum, 8);
      lrow[r] = lrow[r] * alpha + sum;
#pragma unroll
      for (int f = 0; f < 4; ++f) o[f][r] *= alpha;
      p0[r] = e0;
      p1[r] = e1;
    }

    // ---- P (C-layout) -> LDS -> A-operand layout; per-wave double buffer +
    // explicit lgkmcnt(0) drain between writes and read.
    short* P = &Plds[wv][pb][0];
    pb ^= 1;
    asm volatile("" ::: "memory");
#pragma unroll
    for (int r = 0; r < 4; ++r) {
      P[(quad * 4 + r) * 40 + l16]      = f2bf(p0[r]);
      P[(quad * 4 + r) * 40 + 16 + l16] = f2bf(p1[r]);
    }
    asm volatile("" ::: "memory");
    __builtin_amdgcn_s_waitcnt(0xC07F);   // lgkmcnt(0)
    asm volatile("" ::: "memory");
    const bf16x8 pa = *(const bf16x8*)(P + l16 * 40 + quad * 8);
    asm volatile("" ::: "memory");

    // ---- O += P @ V  (V^T: contiguous along keys)
#pragma unroll
    for (int f = 0; f < 4; ++f) {
      bf16x8 vb = *(const bf16x8*)(Vbh + (size_t)(f * 16 + l16) * T_SEQ + k0 + quad * 8);
      o[f] = __builtin_amdgcn_mfma_f32_16x16x32_bf16(pa, vb, o[f], 0, 0, 0);
    }
  }

  // ---- epilogue: normalize + store over this block's own Q region
#pragma unroll
  for (int r = 0; r < 4; ++r) {
    const int q = q0 + quad * 4 + r;
    const float inv = 1.0f / lrow[r];
    short* row = Qp + (size_t)q * DMODEL + l16;
#pragma unroll
    for (int f = 0; f < 4; ++f)
      row[f * 16] = f2bf(o[f][r] * inv);
  }
}

// ---------------------------------------------------------------- launch
extern "C" void kernel_launch(void* const* d_in, const int* in_sizes, int n_in,
                              void* d_out, int out_size, void* d_ws, size_t ws_size,
                              hipStream_t stream) {
  const void* x   = d_in[0];   // [2,4096,1024]
  const void* Wkv = d_in[1];   // [1024,32]
  const void* Wk  = d_in[2];   // [32,1024]
  const void* Wv  = d_in[3];   // [32,1024]
  const void* Wq  = d_in[4];   // [1024,1024]
  const void* Wo  = d_in[5];   // [1024,1024]

  char* p = (char*)d_ws;
  auto carve = [&](size_t n) {
    char* r = p;
    p += (n + 255) & ~(size_t)255;
    return r;
  };
  // total ~69 MB
  int*   flag = (int*)carve(256);
  short* xbf  = (short*)carve((size_t)M_ROWS * DMODEL * 2);   // 16 MB
  short* Qb   = (short*)carve((size_t)M_ROWS * DMODEL * 2);   // 16 MB (Q -> AO)
  short* Kb   = (short*)carve((size_t)M_ROWS * DMODEL * 2);   // 16 MB
  short* Vtb  = (short*)carve((size_t)M_ROWS * DMODEL * 2);   // 16 MB
  short* lat  = (short*)carve((size_t)M_ROWS * LATENT * 2);   // 512 KB
  short* WqT  = (short*)carve((size_t)DMODEL * DMODEL * 2);   // 2 MB
  short* WoT  = (short*)carve((size_t)DMODEL * DMODEL * 2);   // 2 MB
  short* WkvT = (short*)carve((size_t)DMODEL * LATENT * 2);   // 64 KB
  short* WkT  = (short*)carve((size_t)LATENT * DMODEL * 2);   // 64 KB
  short* WvT  = (short*)carve((size_t)LATENT * DMODEL * 2);   // 64 KB

  detect_dtype<<<1, 256, 0, stream>>>((const unsigned short*)x, 1 << 20, flag);

  convert_in<<<(M_ROWS * DMODEL + 255) / 256, 256, 0, stream>>>(x, xbf, M_ROWS * DMODEL, flag);
  convert_transpose<<<(DMODEL * LATENT + 255) / 256, 256, 0, stream>>>(Wkv, WkvT, DMODEL, LATENT, flag);
  convert_transpose<<<(LATENT * DMODEL + 255) / 256, 256, 0, stream>>>(Wk, WkT, LATENT, DMODEL, flag);
  convert_transpose<<<(LATENT * DMODEL + 255) / 256, 256, 0, stream>>>(Wv, WvT, LATENT, DMODEL, flag);
  convert_transpose<<<(DMODEL * DMODEL + 255) / 256, 256, 0, stream>>>(Wq, WqT, DMODEL, DMODEL, flag);
  convert_transpose<<<(DMODEL * DMODEL + 255) / 256, 256, 0, stream>>>(Wo, WoT, DMODEL, DMODEL, flag);

  auto gemm = [&](const short* A, const short* Bt, short* Cs, float* Cf,
                  int M, int K, int N, int mode) {
    int Nw = (N + 63) >> 6;
    int waves = (M / 16) * Nw;
    int blocks = (waves + 3) / 4;
    gemm_bt_kernel<<<blocks, 256, 0, stream>>>(A, Bt, Cs, Cf, flag, M, K, N, mode);
  };

  gemm(xbf, WkvT, lat, nullptr, M_ROWS, DMODEL, LATENT, 0);   // lat = x @ W_kv
  gemm(lat, WkT,  Kb,  nullptr, M_ROWS, LATENT, DMODEL, 0);   // K  [M,1024]
  gemm(lat, WvT,  Vtb, nullptr, M_ROWS, LATENT, DMODEL, 2);   // V^T [B,H,dh,T]
  gemm(xbf, WqT,  Qb,  nullptr, M_ROWS, DMODEL, DMODEL, 0);   // Q  [M,1024]

  attn_kernel<<<BATCH * NHEAD * (T_SEQ / 64), 256, 0, stream>>>(Qb, Kb, Vtb);

  // out = AO @ W_o -> d_out, dtype chosen by flag
  gemm(Qb, WoT, (short*)d_out, (float*)d_out, M_ROWS, DMODEL, DMODEL, 3);
}

// Round 4
// 1223.214 us; speedup vs baseline: 1.5469x; 1.5469x over previous
//
#include <hip/hip_runtime.h>
#include <hip/hip_bf16.h>

// MLA attention. Inputs fp32 (measured: R3 flag==1), internal compute bf16
// MFMA (no fp32 MFMA on CDNA4), output fp32. Pipeline:
//   1. convert x -> bf16 [M,K]; convert+transpose weights -> bf16 [N][K]
//   2. lat = x @ W_kv                  ([M,32])
//   3. K   = lat @ W_k   -> [M,1024]   (head h = cols h*64..h*64+63)
//   4. V   = lat @ W_v   -> [B,H,dh,T] (transposed: PV B-frags contiguous)
//   5. Q   = x @ W_q     -> [M,1024]
//   6. flash attention (mfma 16x16x32, online softmax); overwrites own Q tile
//   7. out = AO @ W_o    -> d_out (fp32)

#define T_SEQ  4096
#define NHEAD  16
#define DHEAD  64
#define DMODEL 1024
#define LATENT 32
#define BATCH  2
#define M_ROWS (BATCH * T_SEQ)

typedef __attribute__((ext_vector_type(8))) short bf16x8;
typedef __attribute__((ext_vector_type(4))) float f32x4;

__device__ __forceinline__ short f2bf(float f) {
  __hip_bfloat16 h = __float2bfloat16(f);
  return __builtin_bit_cast(short, h);
}

// ------------------------------------------------------------- ingress conv
// fp32 -> bf16, 4 elems/thread, coalesced float4 loads.
__global__ __launch_bounds__(256)
void convert_in(const float* __restrict__ src, short* __restrict__ dst, int n) {
  int i = (blockIdx.x * 256 + threadIdx.x) * 4;
  if (i >= n) return;
  const f32x4 v = *(const f32x4*)(src + i);
  short4 o;
  o.x = f2bf(v[0]); o.y = f2bf(v[1]); o.z = f2bf(v[2]); o.w = f2bf(v[3]);
  *(short4*)(dst + i) = o;
}

// convert + transpose: src [K,N] fp32 -> dst [N,K] bf16
__global__ __launch_bounds__(256)
void convert_transpose(const float* __restrict__ src, short* __restrict__ dst,
                       int K, int N) {
  int idx = blockIdx.x * 256 + threadIdx.x;
  if (idx >= K * N) return;
  int k = idx / N;
  int n = idx - k * N;
  dst[n * K + k] = f2bf(src[idx]);
}

// ---------------------------------------------------------------- GEMM
// C[M,N] = A[M,K] @ B[K,N], Bt = B^T ([N][K] row-major, bf16).
// One wave computes a 16(M) x 64(N) tile; 4 waves/block.
// out_mode 0: bf16 row-major [M,N]
// out_mode 2: bf16 [B,H,dh,T] (V^T; requires N==DMODEL)
// out_mode 3: fp32 row-major [M,N]
__global__ __launch_bounds__(256)
void gemm_bt_kernel(const short* __restrict__ A, const short* __restrict__ Bt,
                    short* __restrict__ Cs, float* __restrict__ Cf,
                    int M, int K, int N, int out_mode) {
  const int tid  = threadIdx.x;
  const int wv   = tid >> 6;
  const int lane = tid & 63;
  const int quad = lane >> 4;
  const int l16  = lane & 15;

  const int Nw = (N + 63) >> 6;
  const int gw = blockIdx.x * 4 + wv;
  const int mt = gw / Nw;
  const int nt = gw - mt * Nw;
  const int m0 = mt * 16;
  const int n0 = nt * 64;
  if (m0 >= M) return;

  f32x4 acc[4] = {};
  const short* Ap = A + (size_t)(m0 + l16) * K + quad * 8;

  for (int k0 = 0; k0 < K; k0 += 32) {
    bf16x8 a = *(const bf16x8*)(Ap + k0);
#pragma unroll
    for (int f = 0; f < 4; ++f) {
      const int n = n0 + f * 16 + l16;
      if (n < N) {   // wave-uniform per f (N multiple of 16)
        bf16x8 b = *(const bf16x8*)(Bt + (size_t)n * K + k0 + quad * 8);
        acc[f] = __builtin_amdgcn_mfma_f32_16x16x32_bf16(a, b, acc[f], 0, 0, 0);
      }
    }
  }

#pragma unroll
  for (int f = 0; f < 4; ++f) {
    const int n = n0 + f * 16 + l16;
    if (n >= N) continue;
#pragma unroll
    for (int r = 0; r < 4; ++r) {
      const int m = m0 + quad * 4 + r;     // C/D layout: row=quad*4+r, col=l16
      if (out_mode == 2) {                 // V^T scatter
        const int b  = m >> 12;            // T_SEQ = 4096
        const int t  = m & (T_SEQ - 1);
        const int h  = n >> 6;             // DHEAD = 64
        const int dh = n & 63;
        Cs[((size_t)(b * NHEAD + h) * DHEAD + dh) * T_SEQ + t] = f2bf(acc[f][r]);
      } else if (out_mode == 3) {
        Cf[(size_t)m * N + n] = acc[f][r];
      } else {
        Cs[(size_t)m * N + n] = f2bf(acc[f][r]);
      }
    }
  }
}

// ---------------------------------------------------------------- attention
// One wave per 16-query tile of one (b,h). 32-key steps.
// Q,K natural bf16 [M,1024] (head = col block h*64); V in [B,H,dh,T].
// Output overwrites this block's own Q region (block-private: Q fully read
// into registers before the loop; no other block touches these rows+cols).
__global__ __launch_bounds__(256)
void attn_kernel(short* __restrict__ Qb, const short* __restrict__ Kb,
                 const short* __restrict__ Vt) {
  __shared__ short Plds[4][2][16 * 40];  // per-wave double-buffered 16x32 P

  const int tid  = threadIdx.x;
  const int wv   = tid >> 6;
  const int lane = tid & 63;
  const int quad = lane >> 4;
  const int l16  = lane & 15;

  const int bh = blockIdx.x >> 6;        // 64 q-chunks per (b,h)
  const int qc = blockIdx.x & 63;
  const int q0 = qc * 64 + wv * 16;
  const int b  = bh >> 4;
  const int h  = bh & 15;

  short*       Qp  = Qb + (size_t)b * T_SEQ * DMODEL + h * DHEAD;
  const short* Kp  = Kb + (size_t)b * T_SEQ * DMODEL + h * DHEAD;
  const short* Vbh = Vt + ((size_t)bh) * DHEAD * T_SEQ;   // [dh][T]

  const bf16x8 qa0 = *(const bf16x8*)(Qp + (size_t)(q0 + l16) * DMODEL + quad * 8);
  const bf16x8 qa1 = *(const bf16x8*)(Qp + (size_t)(q0 + l16) * DMODEL + 32 + quad * 8);

  f32x4 o[4] = {};
  float mrow[4], lrow[4];
#pragma unroll
  for (int r = 0; r < 4; ++r) { mrow[r] = -1e30f; lrow[r] = 0.0f; }

  int pb = 0;

  for (int k0 = 0; k0 < q0 + 16; k0 += 32) {
    // ---- S = Q K^T for 16q x 32k
    f32x4 s0 = {}, s1 = {};
    {
      bf16x8 b00 = *(const bf16x8*)(Kp + (size_t)(k0 + l16) * DMODEL + quad * 8);
      bf16x8 b01 = *(const bf16x8*)(Kp + (size_t)(k0 + l16) * DMODEL + 32 + quad * 8);
      s0 = __builtin_amdgcn_mfma_f32_16x16x32_bf16(qa0, b00, s0, 0, 0, 0);
      s0 = __builtin_amdgcn_mfma_f32_16x16x32_bf16(qa1, b01, s0, 0, 0, 0);
      bf16x8 b10 = *(const bf16x8*)(Kp + (size_t)(k0 + 16 + l16) * DMODEL + quad * 8);
      bf16x8 b11 = *(const bf16x8*)(Kp + (size_t)(k0 + 16 + l16) * DMODEL + 32 + quad * 8);
      s1 = __builtin_amdgcn_mfma_f32_16x16x32_bf16(qa0, b10, s1, 0, 0, 0);
      s1 = __builtin_amdgcn_mfma_f32_16x16x32_bf16(qa1, b11, s1, 0, 0, 0);
    }

    // ---- online softmax (C-layout: row=quad*4+r, col=l16; reduce over the
    // 16 lanes of the quad group via xor shuffles 1/2/4/8)
    const int kc0 = k0 + l16;
    const int kc1 = k0 + 16 + l16;
    float p0[4], p1[4];
#pragma unroll
    for (int r = 0; r < 4; ++r) {
      const int q = q0 + quad * 4 + r;
      float v0 = s0[r] * 0.125f;           // 1/sqrt(64)
      float v1 = s1[r] * 0.125f;
      if (kc0 > q) v0 = -1e9f;
      if (kc1 > q) v1 = -1e9f;
      float mx = fmaxf(v0, v1);
      mx = fmaxf(mx, __shfl_xor(mx, 1));
      mx = fmaxf(mx, __shfl_xor(mx, 2));
      mx = fmaxf(mx, __shfl_xor(mx, 4));
      mx = fmaxf(mx, __shfl_xor(mx, 8));
      const float mnew  = fmaxf(mrow[r], mx);
      const float alpha = __expf(mrow[r] - mnew);
      mrow[r] = mnew;
      const float e0 = __expf(v0 - mnew);
      const float e1 = __expf(v1 - mnew);
      float sum = e0 + e1;
      sum += __shfl_xor(sum, 1);
      sum += __shfl_xor(sum, 2);
      sum += __shfl_xor(sum, 4);
      sum += __shfl_xor(sum, 8);
      lrow[r] = lrow[r] * alpha + sum;
#pragma unroll
      for (int f = 0; f < 4; ++f) o[f][r] *= alpha;
      p0[r] = e0;
      p1[r] = e1;
    }

    // ---- P (C-layout) -> LDS -> A-operand layout; per-wave double buffer +
    // explicit lgkmcnt(0) drain between writes and read.
    short* P = &Plds[wv][pb][0];
    pb ^= 1;
    asm volatile("" ::: "memory");
#pragma unroll
    for (int r = 0; r < 4; ++r) {
      P[(quad * 4 + r) * 40 + l16]      = f2bf(p0[r]);
      P[(quad * 4 + r) * 40 + 16 + l16] = f2bf(p1[r]);
    }
    asm volatile("" ::: "memory");
    __builtin_amdgcn_s_waitcnt(0xC07F);   // lgkmcnt(0)
    asm volatile("" ::: "memory");
    const bf16x8 pa = *(const bf16x8*)(P + l16 * 40 + quad * 8);
    asm volatile("" ::: "memory");

    // ---- O += P @ V  (V^T: contiguous along keys)
#pragma unroll
    for (int f = 0; f < 4; ++f) {
      bf16x8 vb = *(const bf16x8*)(Vbh + (size_t)(f * 16 + l16) * T_SEQ + k0 + quad * 8);
      o[f] = __builtin_amdgcn_mfma_f32_16x16x32_bf16(pa, vb, o[f], 0, 0, 0);
    }
  }

  // ---- epilogue: normalize + store over this block's own Q region
#pragma unroll
  for (int r = 0; r < 4; ++r) {
    const int q = q0 + quad * 4 + r;
    const float inv = 1.0f / lrow[r];
    short* row = Qp + (size_t)q * DMODEL + l16;
#pragma unroll
    for (int f = 0; f < 4; ++f)
      row[f * 16] = f2bf(o[f][r] * inv);
  }
}

// ---------------------------------------------------------------- launch
extern "C" void kernel_launch(void* const* d_in, const int* in_sizes, int n_in,
                              void* d_out, int out_size, void* d_ws, size_t ws_size,
                              hipStream_t stream) {
  const float* x   = (const float*)d_in[0];   // [2,4096,1024]
  const float* Wkv = (const float*)d_in[1];   // [1024,32]
  const float* Wk  = (const float*)d_in[2];   // [32,1024]
  const float* Wv  = (const float*)d_in[3];   // [32,1024]
  const float* Wq  = (const float*)d_in[4];   // [1024,1024]
  const float* Wo  = (const float*)d_in[5];   // [1024,1024]

  char* p = (char*)d_ws;
  auto carve = [&](size_t n) {
    char* r = p;
    p += (n + 255) & ~(size_t)255;
    return r;
  };
  // total ~69 MB
  short* xbf  = (short*)carve((size_t)M_ROWS * DMODEL * 2);   // 16 MB
  short* Qb   = (short*)carve((size_t)M_ROWS * DMODEL * 2);   // 16 MB (Q -> AO)
  short* Kb   = (short*)carve((size_t)M_ROWS * DMODEL * 2);   // 16 MB
  short* Vtb  = (short*)carve((size_t)M_ROWS * DMODEL * 2);   // 16 MB
  short* lat  = (short*)carve((size_t)M_ROWS * LATENT * 2);   // 512 KB
  short* WqT  = (short*)carve((size_t)DMODEL * DMODEL * 2);   // 2 MB
  short* WoT  = (short*)carve((size_t)DMODEL * DMODEL * 2);   // 2 MB
  short* WkvT = (short*)carve((size_t)DMODEL * LATENT * 2);   // 64 KB
  short* WkT  = (short*)carve((size_t)LATENT * DMODEL * 2);   // 64 KB
  short* WvT  = (short*)carve((size_t)LATENT * DMODEL * 2);   // 64 KB

  convert_in<<<(M_ROWS * DMODEL / 4 + 255) / 256, 256, 0, stream>>>(x, xbf, M_ROWS * DMODEL);
  convert_transpose<<<(DMODEL * LATENT + 255) / 256, 256, 0, stream>>>(Wkv, WkvT, DMODEL, LATENT);
  convert_transpose<<<(LATENT * DMODEL + 255) / 256, 256, 0, stream>>>(Wk, WkT, LATENT, DMODEL);
  convert_transpose<<<(LATENT * DMODEL + 255) / 256, 256, 0, stream>>>(Wv, WvT, LATENT, DMODEL);
  convert_transpose<<<(DMODEL * DMODEL + 255) / 256, 256, 0, stream>>>(Wq, WqT, DMODEL, DMODEL);
  convert_transpose<<<(DMODEL * DMODEL + 255) / 256, 256, 0, stream>>>(Wo, WoT, DMODEL, DMODEL);

  auto gemm = [&](const short* A, const short* Bt, short* Cs, float* Cf,
                  int M, int K, int N, int mode) {
    int Nw = (N + 63) >> 6;
    int waves = (M / 16) * Nw;
    int blocks = (waves + 3) / 4;
    gemm_bt_kernel<<<blocks, 256, 0, stream>>>(A, Bt, Cs, Cf, M, K, N, mode);
  };

  gemm(xbf, WkvT, lat, nullptr, M_ROWS, DMODEL, LATENT, 0);   // lat = x @ W_kv
  gemm(lat, WkT,  Kb,  nullptr, M_ROWS, LATENT, DMODEL, 0);   // K  [M,1024]
  gemm(lat, WvT,  Vtb, nullptr, M_ROWS, LATENT, DMODEL, 2);   // V^T [B,H,dh,T]
  gemm(xbf, WqT,  Qb,  nullptr, M_ROWS, DMODEL, DMODEL, 0);   // Q  [M,1024]

  attn_kernel<<<BATCH * NHEAD * (T_SEQ / 64), 256, 0, stream>>>(Qb, Kb, Vtb);

  gemm(Qb, WoT, nullptr, (float*)d_out, M_ROWS, DMODEL, DMODEL, 3);  // out fp32
}

// Round 5
// 911.839 us; speedup vs baseline: 2.0751x; 1.3415x over previous
//
#include <hip/hip_runtime.h>
#include <hip/hip_bf16.h>

// MLA attention. Inputs fp32, internal bf16 MFMA, output fp32. Pipeline:
//   1. convert x -> bf16 [M,K]; convert+transpose weights -> bf16 [N][K]
//      (Wq scaled by 1/sqrt(dh) during conversion: S arrives pre-scaled)
//   2. lat = x @ W_kv                  ([M,32])
//   3. K   = lat @ W_k   -> [M,1024]   (head h = cols h*64..h*64+63)
//   4. V   = lat @ W_v   -> [B,H,dh,T] (transposed: PV A-frags contiguous)
//   5. Q   = x @ W_q     -> [M,1024]
//   6. flash attention, TRANSPOSED algebra: S^T = K Q^T (row=key, col=query)
//      -> per-lane-scalar softmax state; O^T = V^T P^T. Overwrites own Q tile.
//   7. out = AO @ W_o    -> d_out (fp32)

#define T_SEQ  4096
#define NHEAD  16
#define DHEAD  64
#define DMODEL 1024
#define LATENT 32
#define BATCH  2
#define M_ROWS (BATCH * T_SEQ)

typedef __attribute__((ext_vector_type(8))) short bf16x8;
typedef __attribute__((ext_vector_type(4))) float f32x4;

__device__ __forceinline__ short f2bf(float f) {
  __hip_bfloat16 h = __float2bfloat16(f);
  return __builtin_bit_cast(short, h);
}

// ------------------------------------------------------------- ingress conv
__global__ __launch_bounds__(256)
void convert_in(const float* __restrict__ src, short* __restrict__ dst, int n) {
  int i = (blockIdx.x * 256 + threadIdx.x) * 4;
  if (i >= n) return;
  const f32x4 v = *(const f32x4*)(src + i);
  short4 o;
  o.x = f2bf(v[0]); o.y = f2bf(v[1]); o.z = f2bf(v[2]); o.w = f2bf(v[3]);
  *(short4*)(dst + i) = o;
}

// convert + transpose (+scale): src [K,N] fp32 -> dst [N,K] bf16
__global__ __launch_bounds__(256)
void convert_transpose(const float* __restrict__ src, short* __restrict__ dst,
                       int K, int N, float scale) {
  int idx = blockIdx.x * 256 + threadIdx.x;
  if (idx >= K * N) return;
  int k = idx / N;
  int n = idx - k * N;
  dst[n * K + k] = f2bf(src[idx] * scale);
}

// ---------------------------------------------------------------- GEMM
// C[M,N] = A[M,K] @ B[K,N], Bt = B^T ([N][K] row-major, bf16).
// One wave computes a 16(M) x 64(N) tile; 4 waves/block.
// out_mode 0: bf16 row-major [M,N]
// out_mode 2: bf16 [B,H,dh,T] (V^T; requires N==DMODEL)
// out_mode 3: fp32 row-major [M,N]
__global__ __launch_bounds__(256)
void gemm_bt_kernel(const short* __restrict__ A, const short* __restrict__ Bt,
                    short* __restrict__ Cs, float* __restrict__ Cf,
                    int M, int K, int N, int out_mode) {
  const int tid  = threadIdx.x;
  const int wv   = tid >> 6;
  const int lane = tid & 63;
  const int quad = lane >> 4;
  const int l16  = lane & 15;

  const int Nw = (N + 63) >> 6;
  const int gw = blockIdx.x * 4 + wv;
  const int mt = gw / Nw;
  const int nt = gw - mt * Nw;
  const int m0 = mt * 16;
  const int n0 = nt * 64;
  if (m0 >= M) return;

  f32x4 acc[4] = {};
  const short* Ap = A + (size_t)(m0 + l16) * K + quad * 8;

  for (int k0 = 0; k0 < K; k0 += 32) {
    bf16x8 a = *(const bf16x8*)(Ap + k0);
#pragma unroll
    for (int f = 0; f < 4; ++f) {
      const int n = n0 + f * 16 + l16;
      if (n < N) {   // wave-uniform per f (N multiple of 16)
        bf16x8 b = *(const bf16x8*)(Bt + (size_t)n * K + k0 + quad * 8);
        acc[f] = __builtin_amdgcn_mfma_f32_16x16x32_bf16(a, b, acc[f], 0, 0, 0);
      }
    }
  }

#pragma unroll
  for (int f = 0; f < 4; ++f) {
    const int n = n0 + f * 16 + l16;
    if (n >= N) continue;
#pragma unroll
    for (int r = 0; r < 4; ++r) {
      const int m = m0 + quad * 4 + r;     // C/D layout: row=quad*4+r, col=l16
      if (out_mode == 2) {                 // V^T scatter
        const int b  = m >> 12;            // T_SEQ = 4096
        const int t  = m & (T_SEQ - 1);
        const int h  = n >> 6;             // DHEAD = 64
        const int dh = n & 63;
        Cs[((size_t)(b * NHEAD + h) * DHEAD + dh) * T_SEQ + t] = f2bf(acc[f][r]);
      } else if (out_mode == 3) {
        Cf[(size_t)m * N + n] = acc[f][r];
      } else {
        Cs[(size_t)m * N + n] = f2bf(acc[f][r]);
      }
    }
  }
}

// ---------------------------------------------------------------- attention
// Transposed flash attention. One wave handles TWO 16-query tiles (pr and
// 255-pr: balanced ~66 iterations for every wave). 64-key steps.
//   S^T = K Q^T : A-frag = K rows (m=key), B-frag = Q^T (n=query=l16)
//   -> C-layout row=key(quad*4+r), col=query(l16): softmax state per-lane
//      scalar, block reduction = 15 in-reg ops + xor16 + xor32.
//   P^T -> LDS as P[query][key] (short4 writes), read back as B-frags
//   O^T = V^T P^T : A-frag = V^T rows (contiguous in [dh][T] layout)
// Output overwrites this wave's own Q tile (wave-private rows+cols).
__global__ __launch_bounds__(256, 4)
void attn_kernel(short* __restrict__ Qb, const short* __restrict__ Kb,
                 const short* __restrict__ Vt) {
  __shared__ short Plds[4][2][16 * 72];   // [wave][dbuf][query][64 keys + pad]

  const int tid  = threadIdx.x;
  const int wv   = tid >> 6;
  const int lane = tid & 63;
  const int quad = lane >> 4;
  const int l16  = lane & 15;

  const int gw = blockIdx.x * 4 + wv;     // 0..4095
  const int bh = gw >> 7;                 // 32 (b,h) pairs
  const int pr = gw & 127;                // tile-pair index
  const int b  = bh >> 4;
  const int h  = bh & 15;

  short*       Qp  = Qb + (size_t)b * T_SEQ * DMODEL + h * DHEAD;
  const short* Kp  = Kb + (size_t)b * T_SEQ * DMODEL + h * DHEAD;
  const short* Vbh = Vt + ((size_t)bh) * DHEAD * T_SEQ;   // [dh][T]

  int pb = 0;

#pragma unroll 1
  for (int half = 0; half < 2; ++half) {
    const int qt   = half ? (255 - pr) : pr;
    const int q0   = qt * 16;
    const int qmax = q0 + 15;
    const int q    = q0 + l16;            // this lane's query (column)

    // Q^T B-fragments: n = l16 (query), k = dh chunk
    const bf16x8 qf0 = *(const bf16x8*)(Qp + (size_t)(q0 + l16) * DMODEL + quad * 8);
    const bf16x8 qf1 = *(const bf16x8*)(Qp + (size_t)(q0 + l16) * DMODEL + 32 + quad * 8);

    f32x4 o[4] = {};
    float m = -1e30f, l = 0.0f;

#pragma unroll 1
    for (int k0 = 0; k0 <= qmax; k0 += 64) {
      // ---- S^T = K Q^T for 64 keys x 16 queries (4 key tiles)
      // (k0 <= 4032 always, so rows k0..k0+63 <= 4095: no OOB; causal mask
      //  handles the overhang keys.)
      f32x4 st[4] = {};
#pragma unroll
      for (int mt = 0; mt < 4; ++mt) {
        const short* kr = Kp + (size_t)(k0 + mt * 16 + l16) * DMODEL + quad * 8;
        const bf16x8 kf0 = *(const bf16x8*)(kr);
        const bf16x8 kf1 = *(const bf16x8*)(kr + 32);
        st[mt] = __builtin_amdgcn_mfma_f32_16x16x32_bf16(kf0, qf0, st[mt], 0, 0, 0);
        st[mt] = __builtin_amdgcn_mfma_f32_16x16x32_bf16(kf1, qf1, st[mt], 0, 0, 0);
      }

      // ---- per-lane softmax over 16 key-scores of query l16
      float sc[4][4];
      float vmax = -1e30f;
#pragma unroll
      for (int mt = 0; mt < 4; ++mt)
#pragma unroll
        for (int r = 0; r < 4; ++r) {
          const int key = k0 + mt * 16 + quad * 4 + r;
          const float v = (key <= q) ? st[mt][r] : -1e9f;   // Wq pre-scaled
          sc[mt][r] = v;
          vmax = fmaxf(vmax, v);
        }
      vmax = fmaxf(vmax, __shfl_xor(vmax, 16));
      vmax = fmaxf(vmax, __shfl_xor(vmax, 32));
      const float mnew  = fmaxf(m, vmax);
      const float alpha = __expf(m - mnew);
      m = mnew;
      float s = 0.0f;
#pragma unroll
      for (int mt = 0; mt < 4; ++mt)
#pragma unroll
        for (int r = 0; r < 4; ++r) {
          sc[mt][r] = __expf(sc[mt][r] - mnew);
          s += sc[mt][r];
        }
      s += __shfl_xor(s, 16);
      s += __shfl_xor(s, 32);
      l = l * alpha + s;
#pragma unroll
      for (int f = 0; f < 4; ++f)
#pragma unroll
        for (int r = 0; r < 4; ++r) o[f][r] *= alpha;

      // ---- P (row=query l16, cols=keys) -> LDS; read back as B-frags.
      // Per-wave double buffer + explicit lgkmcnt(0) drain.
      short* P = &Plds[wv][pb][0];
      pb ^= 1;
      asm volatile("" ::: "memory");
#pragma unroll
      for (int mt = 0; mt < 4; ++mt) {
        short4 w;
        w.x = f2bf(sc[mt][0]); w.y = f2bf(sc[mt][1]);
        w.z = f2bf(sc[mt][2]); w.w = f2bf(sc[mt][3]);
        *(short4*)(P + l16 * 72 + mt * 16 + quad * 4) = w;
      }
      asm volatile("" ::: "memory");
      __builtin_amdgcn_s_waitcnt(0xC07F);   // lgkmcnt(0)
      asm volatile("" ::: "memory");
      const bf16x8 pf0 = *(const bf16x8*)(P + l16 * 72 + quad * 8);
      const bf16x8 pf1 = *(const bf16x8*)(P + l16 * 72 + 32 + quad * 8);
      asm volatile("" ::: "memory");

      // ---- O^T += V^T P^T  (A-frag rows = dh, contiguous over keys)
#pragma unroll
      for (int f = 0; f < 4; ++f) {
        const short* vr = Vbh + (size_t)(f * 16 + l16) * T_SEQ + k0 + quad * 8;
        const bf16x8 vf0 = *(const bf16x8*)(vr);
        const bf16x8 vf1 = *(const bf16x8*)(vr + 32);
        o[f] = __builtin_amdgcn_mfma_f32_16x16x32_bf16(vf0, pf0, o[f], 0, 0, 0);
        o[f] = __builtin_amdgcn_mfma_f32_16x16x32_bf16(vf1, pf1, o[f], 0, 0, 0);
      }
    }

    // ---- epilogue: O^T C-layout row = dh = f*16+quad*4+r, col = query l16.
    // Store short4 over this wave's own Q region.
    const float inv = 1.0f / l;
#pragma unroll
    for (int f = 0; f < 4; ++f) {
      short4 w;
      w.x = f2bf(o[f][0] * inv);
      w.y = f2bf(o[f][1] * inv);
      w.z = f2bf(o[f][2] * inv);
      w.w = f2bf(o[f][3] * inv);
      *(short4*)(Qp + (size_t)(q0 + l16) * DMODEL + f * 16 + quad * 4) = w;
    }
  }
}

// ---------------------------------------------------------------- launch
extern "C" void kernel_launch(void* const* d_in, const int* in_sizes, int n_in,
                              void* d_out, int out_size, void* d_ws, size_t ws_size,
                              hipStream_t stream) {
  const float* x   = (const float*)d_in[0];   // [2,4096,1024]
  const float* Wkv = (const float*)d_in[1];   // [1024,32]
  const float* Wk  = (const float*)d_in[2];   // [32,1024]
  const float* Wv  = (const float*)d_in[3];   // [32,1024]
  const float* Wq  = (const float*)d_in[4];   // [1024,1024]
  const float* Wo  = (const float*)d_in[5];   // [1024,1024]

  char* p = (char*)d_ws;
  auto carve = [&](size_t n) {
    char* r = p;
    p += (n + 255) & ~(size_t)255;
    return r;
  };
  short* xbf  = (short*)carve((size_t)M_ROWS * DMODEL * 2);   // 16 MB
  short* Qb   = (short*)carve((size_t)M_ROWS * DMODEL * 2);   // 16 MB (Q -> AO)
  short* Kb   = (short*)carve((size_t)M_ROWS * DMODEL * 2);   // 16 MB
  short* Vtb  = (short*)carve((size_t)M_ROWS * DMODEL * 2);   // 16 MB
  short* lat  = (short*)carve((size_t)M_ROWS * LATENT * 2);   // 512 KB
  short* WqT  = (short*)carve((size_t)DMODEL * DMODEL * 2);   // 2 MB
  short* WoT  = (short*)carve((size_t)DMODEL * DMODEL * 2);   // 2 MB
  short* WkvT = (short*)carve((size_t)DMODEL * LATENT * 2);   // 64 KB
  short* WkT  = (short*)carve((size_t)LATENT * DMODEL * 2);   // 64 KB
  short* WvT  = (short*)carve((size_t)LATENT * DMODEL * 2);   // 64 KB

  convert_in<<<(M_ROWS * DMODEL / 4 + 255) / 256, 256, 0, stream>>>(x, xbf, M_ROWS * DMODEL);
  convert_transpose<<<(DMODEL * LATENT + 255) / 256, 256, 0, stream>>>(Wkv, WkvT, DMODEL, LATENT, 1.0f);
  convert_transpose<<<(LATENT * DMODEL + 255) / 256, 256, 0, stream>>>(Wk, WkT, LATENT, DMODEL, 1.0f);
  convert_transpose<<<(LATENT * DMODEL + 255) / 256, 256, 0, stream>>>(Wv, WvT, LATENT, DMODEL, 1.0f);
  convert_transpose<<<(DMODEL * DMODEL + 255) / 256, 256, 0, stream>>>(Wq, WqT, DMODEL, DMODEL, 0.125f);
  convert_transpose<<<(DMODEL * DMODEL + 255) / 256, 256, 0, stream>>>(Wo, WoT, DMODEL, DMODEL, 1.0f);

  auto gemm = [&](const short* A, const short* Bt, short* Cs, float* Cf,
                  int M, int K, int N, int mode) {
    int Nw = (N + 63) >> 6;
    int waves = (M / 16) * Nw;
    int blocks = (waves + 3) / 4;
    gemm_bt_kernel<<<blocks, 256, 0, stream>>>(A, Bt, Cs, Cf, M, K, N, mode);
  };

  gemm(xbf, WkvT, lat, nullptr, M_ROWS, DMODEL, LATENT, 0);   // lat = x @ W_kv
  gemm(lat, WkT,  Kb,  nullptr, M_ROWS, LATENT, DMODEL, 0);   // K  [M,1024]
  gemm(lat, WvT,  Vtb, nullptr, M_ROWS, LATENT, DMODEL, 2);   // V^T [B,H,dh,T]
  gemm(xbf, WqT,  Qb,  nullptr, M_ROWS, DMODEL, DMODEL, 0);   // Q (pre-scaled)

  attn_kernel<<<1024, 256, 0, stream>>>(Qb, Kb, Vtb);

  gemm(Qb, WoT, nullptr, (float*)d_out, M_ROWS, DMODEL, DMODEL, 3);  // out fp32
}